// Round 6
// baseline (188.869 us; speedup 1.0000x reference)
//
#include <hip/hip_runtime.h>
#include <hip/hip_bf16.h>

// Problem constants (SelectSphereConv, graph level 6)
#define VN 40962
#define NTASK 5121               // ceil(VN/8): 8 vertices per wave-task
#define XT_BYTES (VN * 512)      // 20,972,544 B for x_t in d_ws
// wf buffer: 2 o-halves x 36 ksteps x 64 lanes x 8 bf16 = 73,728 B after xt

typedef float f32x16 __attribute__((ext_vector_type(16)));
typedef __bf16 bf16x8 __attribute__((ext_vector_type(8)));
typedef unsigned int u32x4 __attribute__((ext_vector_type(4)));

// ---------------------------------------------------------------------------
// Kernel 1: transpose x [256(t=b*64+c), V] f32 -> x_t [V, 256] bf16
// ---------------------------------------------------------------------------
__global__ __launch_bounds__(256) void k_transpose(const float* __restrict__ x,
                                                   __bf16* __restrict__ xt) {
    __shared__ __bf16 tile[64][65];
    const int v0 = blockIdx.x * 64;
    const int t0 = blockIdx.y * 64;
    const int lane = threadIdx.x & 63;
    const int sub = threadIdx.x >> 6;

#pragma unroll
    for (int r = 0; r < 16; ++r) {
        const int t = t0 + r * 4 + sub;
        const int v = v0 + lane;
        float val = (v < VN) ? x[(size_t)t * VN + v] : 0.f;   // coalesced
        tile[r * 4 + sub][lane] = (__bf16)val;
    }
    __syncthreads();
#pragma unroll
    for (int r = 0; r < 16; ++r) {
        const int vv = r * 4 + sub;
        const int v = v0 + vv;
        if (v < VN) xt[(size_t)v * 256 + t0 + lane] = tile[lane][vv];  // coalesced
    }
}

// ---------------------------------------------------------------------------
// Kernel 2: pre-swizzle conv_w into MFMA A-fragment order (bf16), k = j*64+c.
//   wf[(T*36+ks)*64 + lane] (8 bf16): A-row o = 32T + (lane&31),
//   k-octet: j = ks>>2, c = 16*(ks&3) + 8*(lane>>5) + e.
//   (Layout validated end-to-end by round-4 kernel.)
// ---------------------------------------------------------------------------
__global__ __launch_bounds__(64) void k_wprep(const float* __restrict__ conv_w,
                                              __bf16* __restrict__ wf) {
    const int id = blockIdx.x;          // T*36 + ks, 0..71
    const int ks = id % 36;
    const int lane = threadIdx.x;       // 0..63
    const int l31 = lane & 31;
    const int h = lane >> 5;
    const int o = (id / 36) * 32 + l31;
    const int j = ks >> 2;
    const int c0 = 16 * (ks & 3) + 8 * h;
    const float* wrow = conv_w + (size_t)o * 576;
    bf16x8 f;
#pragma unroll
    for (int e = 0; e < 8; ++e) f[e] = (__bf16)wrow[(c0 + e) * 9 + j];
    *(bf16x8*)(wf + ((size_t)id * 64 + lane) * 8) = f;
}

// ---------------------------------------------------------------------------
// Kernel 3: wave-autonomous fused gather + interpolate + conv. No LDS, no
//   barriers. One wave = one task = 8 vertices x all 4 batches x all 64 o.
//   Lane l: (vv = (l&31)>>2, b = l&3, h = l>>5 -> c-octet within k-step).
//   Per q-quadrant: gather 16B/lane of each neighbor row (per-lane, L2-heavy
//   but latency hidden by independent co-resident waves), interp s[9][8]
//   (lane's own c-octet, all j), pack to B-frags, 2 MFMAs per j (o-halves).
//   W A-frags: coalesced 16B/lane loads from the wf buffer (L2-resident).
// ---------------------------------------------------------------------------
__global__ __launch_bounds__(256) void k_main(const __bf16* __restrict__ xt,
                                              const int* __restrict__ index,
                                              const float* __restrict__ itp_mat,
                                              const __bf16* __restrict__ wf,
                                              const float* __restrict__ conv_b,
                                              float* __restrict__ out) {
    const int tid  = threadIdx.x;
    const int lane = tid & 63;
    const int wv   = tid >> 6;
    const int task = blockIdx.x * 4 + wv;    // wave-uniform
    if (task >= NTASK) return;               // no barriers in this kernel

    const int l31 = lane & 31;
    const int h   = lane >> 5;
    const int vv  = l31 >> 2;
    const int b   = l31 & 3;
    const int v0  = task * 8;
    const int v   = v0 + vv;
    const int vm  = (v < VN) ? v : VN - 1;   // clamp for tail task

    // neighbor ids (8 lanes share a vertex -> L1 broadcast)
    const int* idxp = index + (size_t)vm * 9;
    int nb[9];
#pragma unroll
    for (int k = 0; k < 9; ++k) nb[k] = idxp[k];
    const float* amp = itp_mat + (size_t)vm * 81;

    f32x16 acc0, acc1;
#pragma unroll
    for (int r = 0; r < 16; ++r) { acc0[r] = 0.f; acc1[r] = 0.f; }

    const char* gb = (const char*)xt;
    const size_t goff = (size_t)b * 128 + (size_t)h * 16;

#pragma unroll 1
    for (int q = 0; q < 4; ++q) {
        // ---- interp: s[j][e] for this lane's c-octet (c = 16q + 8h + e) ----
        float s[9][8];
#pragma unroll
        for (int j = 0; j < 9; ++j)
#pragma unroll
            for (int e = 0; e < 8; ++e) s[j][e] = 0.f;

#pragma unroll
        for (int k = 0; k < 9; ++k) {
            u32x4 gw = *(const u32x4*)(gb + (size_t)nb[k] * 512 + goff + q * 32);
            float g[8];
#pragma unroll
            for (int d = 0; d < 4; ++d) {
                g[2 * d]     = __builtin_bit_cast(float, gw[d] << 16);
                g[2 * d + 1] = __builtin_bit_cast(float, gw[d] & 0xffff0000u);
            }
#pragma unroll
            for (int j = 0; j < 9; ++j) {
                const float a = amp[k * 9 + j];
#pragma unroll
                for (int e = 0; e < 8; ++e) s[j][e] += g[e] * a;
            }
        }

        // ---- 18 MFMAs: ks = 4j + q, two o-halves ----
#pragma unroll
        for (int j = 0; j < 9; ++j) {
            bf16x8 bfr;
#pragma unroll
            for (int e = 0; e < 8; ++e) bfr[e] = (__bf16)s[j][e];
            const int ks = 4 * j + q;
            bf16x8 a0 = *(const bf16x8*)(wf + ((size_t)ks * 64 + lane) * 8);
            bf16x8 a1 = *(const bf16x8*)(wf + ((size_t)(36 + ks) * 64 + lane) * 8);
            acc0 = __builtin_amdgcn_mfma_f32_32x32x16_bf16(a0, bfr, acc0, 0, 0, 0);
            acc1 = __builtin_amdgcn_mfma_f32_32x32x16_bf16(a1, bfr, acc1, 0, 0, 0);
        }
    }

    // ---- store: out[(b*64 + o)*VN + v]; o = (r&3)+8*(r>>2)+4h (+32 for acc1)
    //      8 lanes (vv 0..7, same b,o) write v0..v0+7 in the same instruction
    //      -> 32B-dense sectors.
    if (v < VN) {
        float* ob = out + (size_t)b * 64 * VN + v;
#pragma unroll
        for (int r = 0; r < 16; ++r) {
            const int ol = (r & 3) + 8 * (r >> 2) + 4 * h;
            ob[(size_t)ol * VN]        = acc0[r] + conv_b[ol];
            ob[(size_t)(32 + ol) * VN] = acc1[r] + conv_b[32 + ol];
        }
    }
}

// ---------------------------------------------------------------------------
extern "C" void kernel_launch(void* const* d_in, const int* in_sizes, int n_in,
                              void* d_out, int out_size, void* d_ws, size_t ws_size,
                              hipStream_t stream) {
    const float* x       = (const float*)d_in[0];
    const int*   index   = (const int*)d_in[1];
    const float* itp_mat = (const float*)d_in[2];
    const float* conv_w  = (const float*)d_in[3];
    const float* conv_b  = (const float*)d_in[4];
    float* out = (float*)d_out;

    __bf16* xt = (__bf16*)d_ws;                          // 20,972,544 B
    __bf16* wfrag = (__bf16*)((char*)d_ws + XT_BYTES);   // + 73,728 B

    dim3 tgrid((VN + 63) / 64, 4, 1);
    k_transpose<<<tgrid, 256, 0, stream>>>(x, xt);
    k_wprep<<<72, 64, 0, stream>>>(conv_w, wfrag);
    k_main<<<(NTASK + 3) / 4, 256, 0, stream>>>(xt, index, itp_mat, wfrag,
                                                conv_b, out);
}

// Round 7
// 97.348 us; speedup vs baseline: 1.9401x; 1.9401x over previous
//
#include <hip/hip_runtime.h>
#include <hip/hip_bf16.h>

// Problem constants (SelectSphereConv, graph level 6)
#define VN 40962
#define NG 10241          // groups of 4 vertices, one per block
#define LDA_B 1168        // A-tile row stride bytes (576*2 + 16 pad)
#define OFF_C 18688       // C staging after 16-row A-tile
#define LDS_TOT 23040     // 18688 + 16*68*4
#define XT_BYTES (VN * 512)

typedef float f32x4 __attribute__((ext_vector_type(4)));
typedef float f32x2 __attribute__((ext_vector_type(2)));
typedef __bf16 bf16x8 __attribute__((ext_vector_type(8)));

// ---------------------------------------------------------------------------
// Kernel 1: transpose x [256(t=b*64+c), V] f32 -> x_t [V, 256] bf16
// ---------------------------------------------------------------------------
__global__ __launch_bounds__(256) void k_transpose(const float* __restrict__ x,
                                                   __bf16* __restrict__ xt) {
    __shared__ __bf16 tile[64][65];
    const int v0 = blockIdx.x * 64;
    const int t0 = blockIdx.y * 64;
    const int lane = threadIdx.x & 63;
    const int sub = threadIdx.x >> 6;

#pragma unroll
    for (int r = 0; r < 16; ++r) {
        const int t = t0 + r * 4 + sub;
        const int v = v0 + lane;
        float val = (v < VN) ? x[(size_t)t * VN + v] : 0.f;   // coalesced
        tile[r * 4 + sub][lane] = (__bf16)val;
    }
    __syncthreads();
#pragma unroll
    for (int r = 0; r < 16; ++r) {
        const int vv = r * 4 + sub;
        const int v = v0 + vv;
        if (v < VN) xt[(size_t)v * 256 + t0 + lane] = tile[lane][vv];  // coalesced
    }
}

// ---------------------------------------------------------------------------
// Kernel 2: pre-swizzle conv_w into 16x16x32 B-fragment order (R1-validated):
//   wf[((w*18+ks)*64 + lane)*8 + e] = conv_w[(w*16+(lane&15))*576
//                                            + ks*32 + (lane>>4)*8 + e]
// ---------------------------------------------------------------------------
__global__ __launch_bounds__(64) void k_wprep(const float* __restrict__ conv_w,
                                              __bf16* __restrict__ wf) {
    const int id = blockIdx.x;           // w*18 + ks, 0..71
    const int ks = id % 18;
    const int w  = id / 18;
    const int lane = threadIdx.x;        // 0..63
    const int o  = w * 16 + (lane & 15);
    const int kb = (lane >> 4) * 8;
    const float* wrow = conv_w + (size_t)o * 576 + ks * 32 + kb;
    bf16x8 f;
#pragma unroll
    for (int e = 0; e < 8; ++e) f[e] = (__bf16)wrow[e];
    *(bf16x8*)(wf + ((size_t)id * 64 + lane) * 8) = f;
}

// ---------------------------------------------------------------------------
// Kernel 3: fused gather + interpolate + conv. ONE group (4 vertices) per
//   block, 23 KB LDS -> up to 7 blocks/CU; occupancy (many independent,
//   barrier-staggered contexts) hides the per-group latency chain that
//   capped R1/R3/R5. W-fragments streamed from wf (L2-resident, coalesced
//   1KB/wave loads) to keep VGPRs low. 2 barriers total.
// ---------------------------------------------------------------------------
__global__ __launch_bounds__(256) void k_fused(const __bf16* __restrict__ xt,
                                               const int* __restrict__ index,
                                               const float* __restrict__ itp_mat,
                                               const __bf16* __restrict__ wf,
                                               const float* __restrict__ conv_b,
                                               float* __restrict__ out) {
    __shared__ char smem[LDS_TOT];

    const int tid  = threadIdx.x;
    const int lane = tid & 63;
    const int w    = tid >> 6;      // batch b in phase 1 / epilogue; o-tile in MFMA
    const int l16  = lane & 15;
    const int g4   = lane >> 4;
    const int v0   = blockIdx.x * 4;

    // ---------------- phase 1: gather + interpolate ----------------
    // thread t = (b = w, c = lane); gathers xt[nb*256 + t] (2B, 128B/wave)
#pragma unroll 2
    for (int vv = 0; vv < 4; ++vv) {
        const int v  = v0 + vv;
        const int vm = (v < VN) ? v : VN - 1;           // clamp tail
        const int* idxv = index + (size_t)vm * 9;       // uniform -> s_load
        const float* am = itp_mat + (size_t)vm * 81;    // uniform -> s_load
        float gv[9];
#pragma unroll
        for (int k = 0; k < 9; ++k)
            gv[k] = (float)xt[(size_t)idxv[k] * 256 + tid];
        float s[9];
#pragma unroll
        for (int j = 0; j < 9; ++j) s[j] = 0.f;
#pragma unroll
        for (int k = 0; k < 9; ++k) {
            const float gk = gv[k];
#pragma unroll
            for (int j = 0; j < 9; ++j) s[j] += gk * am[k * 9 + j];
        }
        __bf16* rowp = (__bf16*)(smem + (vv * 4 + w) * LDA_B) + lane * 9;
#pragma unroll
        for (int j = 0; j < 9; ++j) rowp[j] = (__bf16)s[j];
    }
    __syncthreads();

    // ---------------- phase 2: MFMA (A = itp tile, B = streamed W) --------
    f32x4 acc = {0.f, 0.f, 0.f, 0.f};
    {
        const char* ar = smem + l16 * LDA_B + g4 * 16;
        const __bf16* wfp = wf + ((size_t)(w * 18) * 64 + lane) * 8;
#pragma unroll
        for (int ks = 0; ks < 18; ++ks) {
            bf16x8 a  = *(const bf16x8*)(ar + ks * 64);
            bf16x8 wb = *(const bf16x8*)(wfp + (size_t)ks * 512);
            acc = __builtin_amdgcn_mfma_f32_16x16x32_bf16(a, wb, acc, 0, 0, 0);
        }
    }
    // C staging (separate LDS region; no barrier needed before writes)
    {
        float* c_lds = (float*)(smem + OFF_C);
#pragma unroll
        for (int r = 0; r < 4; ++r)
            c_lds[(g4 * 4 + r) * 68 + w * 16 + l16] = acc[r];
    }
    __syncthreads();

    // ---------------- epilogue: thread (b = w, o = lane) ----------------
    {
        const float* c_lds = (const float*)(smem + OFF_C);
        const float bias_v = conv_b[lane];
        float vals[4];
#pragma unroll
        for (int vv = 0; vv < 4; ++vv)
            vals[vv] = c_lds[(vv * 4 + w) * 68 + lane] + bias_v;
        float* op = out + (size_t)tid * VN + v0;   // out[(b*64+o)*V + v]
        const int vleft = VN - v0;
        if (vleft >= 4) {
            *(f32x2*)op       = f32x2{vals[0], vals[1]};
            *(f32x2*)(op + 2) = f32x2{vals[2], vals[3]};
        } else {
#pragma unroll
            for (int vv = 0; vv < 4; ++vv) if (vv < vleft) op[vv] = vals[vv];
        }
    }
}

// ---------------------------------------------------------------------------
extern "C" void kernel_launch(void* const* d_in, const int* in_sizes, int n_in,
                              void* d_out, int out_size, void* d_ws, size_t ws_size,
                              hipStream_t stream) {
    const float* x       = (const float*)d_in[0];
    const int*   index   = (const int*)d_in[1];
    const float* itp_mat = (const float*)d_in[2];
    const float* conv_w  = (const float*)d_in[3];
    const float* conv_b  = (const float*)d_in[4];
    float* out = (float*)d_out;

    __bf16* xt = (__bf16*)d_ws;                          // 20,972,544 B
    __bf16* wfrag = (__bf16*)((char*)d_ws + XT_BYTES);   // + 73,728 B

    dim3 tgrid((VN + 63) / 64, 4, 1);
    k_transpose<<<tgrid, 256, 0, stream>>>(x, xt);
    k_wprep<<<72, 64, 0, stream>>>(conv_w, wfrag);
    k_fused<<<NG, 256, 0, stream>>>(xt, index, itp_mat, wfrag, conv_b, out);
}